// Round 23
// baseline (152.300 us; speedup 1.0000x reference)
//
#include <hip/hip_runtime.h>
#include <hip/hip_bf16.h>

#define S_LEN 4096
#define B_SZ 2
#define DM 1024
#define NH 16
#define DH 64

typedef __attribute__((ext_vector_type(8))) short short8;
typedef __attribute__((ext_vector_type(4))) float f32x4;

__device__ __forceinline__ ushort f2b(float f) {
  union { __hip_bfloat16 b; ushort u; } cv;
  cv.b = __float2bfloat16(f);
  return cv.u;
}

__device__ __forceinline__ void glds16(const ushort* g, ushort* l) {
  __builtin_amdgcn_global_load_lds(
      (const __attribute__((address_space(1))) void*)g,
      (__attribute__((address_space(3))) void*)l, 16, 0, 0);
}

// ---------------- merged fp32 -> bf16 convert ----------------
__global__ void cvt_all(const float* __restrict__ q, const float* __restrict__ k,
                        const float* __restrict__ v, const float* __restrict__ wq,
                        const float* __restrict__ wk, const float* __restrict__ wv,
                        const float* __restrict__ wo, ushort* __restrict__ dst) {
  const int NX4 = 2097152;  // 8M/4
  const int NW4 = 262144;   // 1M/4
  const int total = 3 * NX4 + 4 * NW4;
  for (int i = blockIdx.x * blockDim.x + threadIdx.x; i < total;
       i += gridDim.x * blockDim.x) {
    const float* s;
    int j;
    if (i < NX4) { s = q; j = i; }
    else if (i < 2 * NX4) { s = k; j = i - NX4; }
    else if (i < 3 * NX4) { s = v; j = i - 2 * NX4; }
    else {
      int t = i - 3 * NX4;
      int wsel = t >> 18;
      j = t & (NW4 - 1);
      s = wsel == 0 ? wq : wsel == 1 ? wk : wsel == 2 ? wv : wo;
    }
    float4 val = reinterpret_cast<const float4*>(s)[j];
    ushort4 o;
    o.x = f2b(val.x); o.y = f2b(val.y); o.z = f2b(val.z); o.w = f2b(val.w);
    reinterpret_cast<ushort4*>(dst)[i] = o;
  }
}

// swizzled LDS read: XOR row bits 0-2 into byte-col bits 4-6 (128B rows)
__device__ __forceinline__ short8 ldsrd(const ushort* base, int row, int cb) {
  const int pcb = cb ^ ((row & 7) << 4);
  return *reinterpret_cast<const short8*>(
      reinterpret_cast<const char*>(base) + row * 128 + pcb);
}

// ---------------- 3-deep pipelined bt-GEMM (round-6 proven) ----------------
template <int MODE>
__launch_bounds__(512, 2)
__global__ void gemmP(const ushort* __restrict__ A0, const ushort* __restrict__ A1,
                      const ushort* __restrict__ A2, const ushort* __restrict__ W0,
                      const ushort* __restrict__ W1, const ushort* __restrict__ W2,
                      void* __restrict__ O0, void* __restrict__ O1,
                      void* __restrict__ O2) {
  __shared__ ushort As[3][16384];  // 256x64 each, 96 KB
  __shared__ ushort Bs[3][8192];   // 128x64 each, 48 KB
  const int tid = threadIdx.x;
  const int lane = tid & 63, w = tid >> 6;
  const int wm = w >> 1, wn = w & 1;
  const int g = lane >> 4, lr = lane & 15;
  const int m0 = blockIdx.x * 256;
  const int ysel = (MODE == 0) ? (blockIdx.y >> 3) : 0;
  const ushort* A = (MODE == 0) ? (ysel == 0 ? A0 : ysel == 1 ? A1 : A2) : A0;
  const ushort* W = (MODE == 0) ? (ysel == 0 ? W0 : ysel == 1 ? W1 : W2) : W0;
  const int n0 = ((MODE == 0) ? (blockIdx.y & 7) : blockIdx.y) * 128;

  const int row_r = tid >> 3;
  const int cb = ((tid & 7) * 16) ^ ((row_r & 7) << 4);
  const ushort* Asrc = A + (size_t)(m0 + row_r) * DM + (cb >> 1);
  const ushort* Wsrc = W + (size_t)(n0 + row_r) * DM + (cb >> 1);

#define STG_ALL(bs, kt)                                                      \
  { const int kq = (kt) * 64;                                                \
    glds16(Asrc + kq,                        &As[bs][w * 512]);              \
    glds16(Asrc + (size_t)64 * DM + kq,      &As[bs][4096 + w * 512]);       \
    glds16(Asrc + (size_t)128 * DM + kq,     &As[bs][8192 + w * 512]);       \
    glds16(Asrc + (size_t)192 * DM + kq,     &As[bs][12288 + w * 512]);      \
    glds16(Wsrc + kq,                        &Bs[bs][w * 512]);              \
    glds16(Wsrc + (size_t)64 * DM + kq,      &Bs[bs][4096 + w * 512]); }

  f32x4 acc[4][4] = {};
  short8 af[4][2], b0[2][2], b1[2][2];

  STG_ALL(0, 0);
  STG_ALL(1, 1);

  int bc = 0;
  for (int kt = 0; kt < 16; ++kt) {
    const int bs = bc >= 1 ? bc - 1 : bc + 2;  // (bc+2)%3
    const int tn = kt + 2 < 16 ? kt + 2 : 15;
    asm volatile("s_waitcnt vmcnt(6)" ::: "memory");
    __builtin_amdgcn_s_barrier();
    __builtin_amdgcn_sched_barrier(0);
    const ushort* Ab = &As[bc][0];
    const ushort* Bb = &Bs[bc][0];
#pragma unroll
    for (int m = 0; m < 4; m++)
#pragma unroll
      for (int kk = 0; kk < 2; kk++)
        af[m][kk] = ldsrd(Ab, wm * 64 + m * 16 + lr, kk * 64 + g * 16);
#pragma unroll
    for (int n = 0; n < 2; n++)
#pragma unroll
      for (int kk = 0; kk < 2; kk++) {
        b0[n][kk] = ldsrd(Bb, wn * 64 + n * 16 + lr, kk * 64 + g * 16);
        b1[n][kk] = ldsrd(Bb, wn * 64 + 32 + n * 16 + lr, kk * 64 + g * 16);
      }
    STG_ALL(bs, tn);
    __builtin_amdgcn_sched_barrier(0);
    asm volatile("s_waitcnt lgkmcnt(0)" ::: "memory");
    __builtin_amdgcn_sched_barrier(0);
    __builtin_amdgcn_s_setprio(1);
#pragma unroll
    for (int m = 0; m < 4; m++)
#pragma unroll
      for (int n = 0; n < 2; n++)
#pragma unroll
        for (int kk = 0; kk < 2; kk++)
          acc[m][n] = __builtin_amdgcn_mfma_f32_16x16x32_bf16(af[m][kk], b0[n][kk],
                                                              acc[m][n], 0, 0, 0);
#pragma unroll
    for (int m = 0; m < 4; m++)
#pragma unroll
      for (int n = 0; n < 2; n++)
#pragma unroll
        for (int kk = 0; kk < 2; kk++)
          acc[m][2 + n] = __builtin_amdgcn_mfma_f32_16x16x32_bf16(af[m][kk], b1[n][kk],
                                                                  acc[m][2 + n], 0, 0, 0);
    __builtin_amdgcn_s_setprio(0);
    __builtin_amdgcn_sched_barrier(0);
    bc = bc + 1 == 3 ? 0 : bc + 1;
  }
#undef STG_ALL

  const int colB = n0 + wn * 64;
#pragma unroll
  for (int m = 0; m < 4; ++m) {
    const int row0 = m0 + wm * 64 + m * 16 + g * 4;
#pragma unroll
    for (int n = 0; n < 4; ++n) {
      const int col = colB + n * 16 + lr;
      if (MODE == 2) {
#pragma unroll
        for (int r = 0; r < 4; r++)
          reinterpret_cast<float*>(O0)[(size_t)(row0 + r) * DM + col] = acc[m][n][r];
      } else if (ysel == 0 || ysel == 1) {
        ushort* O = reinterpret_cast<ushort*>(ysel == 0 ? O0 : O1);
#pragma unroll
        for (int r = 0; r < 4; r++)
          O[(size_t)(row0 + r) * DM + col] = f2b(acc[m][n][r]);
      } else {
        const int b = row0 >> 12, s0 = row0 & 4095;
        const int h = col >> 6, dk = col & 63;
        ushort4 o;
        o.x = f2b(acc[m][n][0]); o.y = f2b(acc[m][n][1]);
        o.z = f2b(acc[m][n][2]); o.w = f2b(acc[m][n][3]);
        *reinterpret_cast<ushort4*>(
            reinterpret_cast<ushort*>(O2) +
            (((size_t)(b * NH + h) * DH + dk) << 12) + s0) = o;
      }
    }
  }
}

// ---------------- local attention, KVBLK=128: 3 K-tiles per q-block ----------------
// Window span 384 = 3x128 exactly: tile k0==q0 fully interior, others edge.
// K double-buffered [2][128x64] (prefetch next tile); V single-buffered
// [64x128], staged THIS iter, consumed at PV behind counted vmcnt:
//   outstanding after stages = (pfK?2:0) K-loads + 2 V-loads
//   -> wait vmcnt(pfK?2:0): V landed, K-prefetch stays in flight.
// V-overwrite safe: iter-start barrier proves all waves finished PV(prev).
// PV in two 64-key halves reusing Ps[w] (wave-private, lgkm-ordered).
// LDS 66 KB -> 2 blocks/CU.
__global__ void attn_local(const ushort* __restrict__ Qp, const ushort* __restrict__ Kp,
                           const ushort* __restrict__ Vt, ushort* __restrict__ Ao) {
  __shared__ ushort Ks[2][8192];   // 128 keys x 64 dk (16 KB each)
  __shared__ ushort Vs[8192];      // 64 dk x 128 keys (16 KB)
  __shared__ ushort Ps[8][16 * 72];
  const int tid = threadIdx.x;
  const int lane = tid & 63;
  const int w = tid >> 6;          // 0..7
  const int g = lane >> 4, lr = lane & 15;
  const int bh = blockIdx.y, b = bh >> 4, h = bh & 15;
  const int qt = ((blockIdx.x & 7) << 2) + (blockIdx.x >> 3);  // XCD-contiguous
  const int q0 = qt * 128;

  const float C_SCALE = 0.125f * 1.44269504f;
  const float C_M = 8.0f * 1.44269504f;

  const int qrow = q0 + w * 16 + lr;
  const ushort* qptr = Qp + ((size_t)b * S_LEN + qrow) * DM + h * DH;
  short8 qf[2];
  qf[0] = *reinterpret_cast<const short8*>(qptr + g * 8);
  qf[1] = *reinterpret_cast<const short8*>(qptr + 32 + g * 8);

  float l_r[4] = {0.f, 0.f, 0.f, 0.f};
  f32x4 acc_o[4] = {};

  // K staging: row tid>>3 (0..63, +64 2nd issue), 16B chunk tid&7
  const int sr = tid >> 3;
  const int scb = (tid & 7) * 16;
  const int cbk = scb ^ ((sr & 7) << 4);
  // V staging: dk row tid>>4 (0..31, +32 2nd issue), 16B chunk tid&15 of 256B row
  const int vrow = tid >> 4;
  const int vcb = ((tid & 15) * 16) ^ ((vrow & 7) << 4);

  const int t_lo = q0 >= 128 ? q0 - 128 : 0;
  const int t_hi = (q0 + 256) <= S_LEN ? (q0 + 256) : S_LEN;

#define STAGE_K(bb, kk0)                                                      \
  { glds16(Kp + ((size_t)b * S_LEN + (kk0) + sr) * DM + h * DH + cbk / 2,     \
           &Ks[bb][w * 512]);                                                 \
    glds16(Kp + ((size_t)b * S_LEN + (kk0) + 64 + sr) * DM + h * DH + cbk / 2,\
           &Ks[bb][4096 + w * 512]); }
#define STAGE_V(kk0)                                                          \
  { glds16(Vt + (((size_t)bh * DH + vrow) << 12) + (kk0) + vcb / 2,           \
           &Vs[w * 512]);                                                     \
    glds16(Vt + (((size_t)bh * DH + 32 + vrow) << 12) + (kk0) + vcb / 2,      \
           &Vs[4096 + w * 512]); }

  STAGE_K(0, t_lo);

  int it = 0;
  for (int k0 = t_lo; k0 < t_hi; k0 += 128, ++it) {
    const int cur = it & 1;
    const bool pfK = (k0 + 128 < t_hi);
    asm volatile("s_waitcnt vmcnt(0)" ::: "memory");
    __builtin_amdgcn_s_barrier();
    __builtin_amdgcn_sched_barrier(0);
    if (pfK) STAGE_K(cur ^ 1, k0 + 128);
    STAGE_V(k0);
    __builtin_amdgcn_sched_barrier(0);

    // ---- QK^T over 128 keys (16-MFMA run) ----
    f32x4 sc[8] = {};
    __builtin_amdgcn_s_setprio(1);
#pragma unroll
    for (int kk = 0; kk < 2; kk++) {
#pragma unroll
      for (int nt = 0; nt < 8; nt++) {
        const int kr = nt * 16 + lr;
        const int cb2 = (kk * 64 + g * 16) ^ ((kr & 7) << 4);
        short8 kf = *reinterpret_cast<const short8*>(
            reinterpret_cast<const char*>(&Ks[cur][0]) + kr * 128 + cb2);
        sc[nt] = __builtin_amdgcn_mfma_f32_16x16x32_bf16(qf[kk], kf, sc[nt], 0, 0, 0);
      }
    }
    __builtin_amdgcn_s_setprio(0);

    // ---- fixed-max softmax (exact) ----
    const bool edge = (k0 != q0);
    if (edge) {
#pragma unroll
      for (int nt = 0; nt < 8; nt++) {
        const int key = k0 + nt * 16 + lr;
#pragma unroll
        for (int r = 0; r < 4; r++) {
          const int qr = q0 + w * 16 + g * 4 + r;
          int d = qr - key; d = d < 0 ? -d : d;
          float arg = fmaf(sc[nt][r], C_SCALE, -C_M);
          arg = (d <= 128) ? arg : -400.f;
          const float p = exp2f(arg);
          sc[nt][r] = p;
          l_r[r] += p;
        }
      }
    } else {
#pragma unroll
      for (int nt = 0; nt < 8; nt++)
#pragma unroll
        for (int r = 0; r < 4; r++) {
          const float p = exp2f(fmaf(sc[nt][r], C_SCALE, -C_M));
          sc[nt][r] = p;
          l_r[r] += p;
        }
    }

    // ---- V visibility: wait own V loads (leave K prefetch in flight), then barrier ----
    if (pfK) {
      asm volatile("s_waitcnt vmcnt(2)" ::: "memory");
    } else {
      asm volatile("s_waitcnt vmcnt(0)" ::: "memory");
    }
    __builtin_amdgcn_s_barrier();
    __builtin_amdgcn_sched_barrier(0);

    // ---- PV in two 64-key halves ----
    ushort* myP = Ps[w];
#pragma unroll
    for (int hh = 0; hh < 2; ++hh) {
#pragma unroll
      for (int nt = 0; nt < 4; nt++)
#pragma unroll
        for (int r = 0; r < 4; r++)
          myP[(g * 4 + r) * 72 + nt * 16 + lr] = f2b(sc[hh * 4 + nt][r]);
      asm volatile("s_waitcnt lgkmcnt(0)" ::: "memory");
      __builtin_amdgcn_sched_barrier(0);
      __builtin_amdgcn_s_setprio(1);
#pragma unroll
      for (int kk2 = 0; kk2 < 2; kk2++) {
        short8 pf2 = *reinterpret_cast<const short8*>(myP + lr * 72 + kk2 * 32 + g * 8);
#pragma unroll
        for (int nt = 0; nt < 4; nt++) {
          const int vr = nt * 16 + lr;
          const int pcb = (hh * 128 + kk2 * 64 + g * 16) ^ ((vr & 7) << 4);
          short8 vf = *reinterpret_cast<const short8*>(
              reinterpret_cast<const char*>(&Vs[0]) + vr * 256 + pcb);
          acc_o[nt] = __builtin_amdgcn_mfma_f32_16x16x32_bf16(pf2, vf, acc_o[nt], 0, 0, 0);
        }
      }
      __builtin_amdgcn_s_setprio(0);
      __builtin_amdgcn_sched_barrier(0);
    }
  }
#undef STAGE_K
#undef STAGE_V

  float inv[4];
#pragma unroll
  for (int r = 0; r < 4; r++) {
    float l = l_r[r];
    l += __shfl_xor(l, 1);
    l += __shfl_xor(l, 2);
    l += __shfl_xor(l, 4);
    l += __shfl_xor(l, 8);
    inv[r] = 1.0f / l;
  }
  const int qr0 = q0 + w * 16 + g * 4;
  ushort* orow = Ao + (size_t)b * S_LEN * DM + h * DH;
#pragma unroll
  for (int nt = 0; nt < 4; nt++)
#pragma unroll
    for (int r = 0; r < 4; r++)
      orow[(size_t)(qr0 + r) * DM + nt * 16 + lr] = f2b(acc_o[nt][r] * inv[r]);
}

extern "C" void kernel_launch(void* const* d_in, const int* in_sizes, int n_in,
                              void* d_out, int out_size, void* d_ws, size_t ws_size,
                              hipStream_t stream) {
  const float* q  = (const float*)d_in[0];
  const float* k  = (const float*)d_in[1];
  const float* v  = (const float*)d_in[2];
  const float* wq = (const float*)d_in[3];
  const float* wk = (const float*)d_in[4];
  const float* wv = (const float*)d_in[5];
  const float* wo = (const float*)d_in[6];

  const size_t NX = (size_t)B_SZ * S_LEN * DM;  // 8388608
  const size_t NW = (size_t)DM * DM;            // 1048576
  if (ws_size < (7 * NX + 4 * NW) * sizeof(ushort)) return;

  ushort* ws  = (ushort*)d_ws;
  ushort* qb  = ws;
  ushort* kb  = qb + NX;
  ushort* vb  = kb + NX;
  ushort* wqb = vb + NX;
  ushort* wkb = wqb + NW;
  ushort* wvb = wkb + NW;
  ushort* wob = wvb + NW;
  ushort* Qp  = wob + NW;
  ushort* Kp  = Qp + NX;
  ushort* Vt  = Kp + NX;
  ushort* Ao  = Vt + NX;

  cvt_all<<<dim3(2048), dim3(256), 0, stream>>>(q, k, v, wq, wk, wv, wo, ws);

  gemmP<0><<<dim3(32, 24), dim3(512), 0, stream>>>(qb, kb, vb, wqb, wkb, wvb,
                                                   Qp, Kp, Vt);

  attn_local<<<dim3(32, 32), dim3(512), 0, stream>>>(Qp, Kp, Vt, Ao);

  gemmP<2><<<dim3(32, 8), dim3(512), 0, stream>>>(Ao, Ao, Ao, wob, wob, wob,
                                                  d_out, d_out, d_out);
}

// Round 24
// 150.159 us; speedup vs baseline: 1.0143x; 1.0143x over previous
//
#include <hip/hip_runtime.h>
#include <hip/hip_bf16.h>

#define S_LEN 4096
#define B_SZ 2
#define DM 1024
#define NH 16
#define DH 64

typedef __attribute__((ext_vector_type(8))) short short8;
typedef __attribute__((ext_vector_type(4))) float f32x4;

__device__ __forceinline__ ushort f2b(float f) {
  union { __hip_bfloat16 b; ushort u; } cv;
  cv.b = __float2bfloat16(f);
  return cv.u;
}

__device__ __forceinline__ void glds16(const ushort* g, ushort* l) {
  __builtin_amdgcn_global_load_lds(
      (const __attribute__((address_space(1))) void*)g,
      (__attribute__((address_space(3))) void*)l, 16, 0, 0);
}

// ---------------- merged fp32 -> bf16 convert ----------------
__global__ void cvt_all(const float* __restrict__ q, const float* __restrict__ k,
                        const float* __restrict__ v, const float* __restrict__ wq,
                        const float* __restrict__ wk, const float* __restrict__ wv,
                        const float* __restrict__ wo, ushort* __restrict__ dst) {
  const int NX4 = 2097152;  // 8M/4
  const int NW4 = 262144;   // 1M/4
  const int total = 3 * NX4 + 4 * NW4;
  for (int i = blockIdx.x * blockDim.x + threadIdx.x; i < total;
       i += gridDim.x * blockDim.x) {
    const float* s;
    int j;
    if (i < NX4) { s = q; j = i; }
    else if (i < 2 * NX4) { s = k; j = i - NX4; }
    else if (i < 3 * NX4) { s = v; j = i - 2 * NX4; }
    else {
      int t = i - 3 * NX4;
      int wsel = t >> 18;
      j = t & (NW4 - 1);
      s = wsel == 0 ? wq : wsel == 1 ? wk : wsel == 2 ? wv : wo;
    }
    float4 val = reinterpret_cast<const float4*>(s)[j];
    ushort4 o;
    o.x = f2b(val.x); o.y = f2b(val.y); o.z = f2b(val.z); o.w = f2b(val.w);
    reinterpret_cast<ushort4*>(dst)[i] = o;
  }
}

// swizzled LDS read: XOR row bits 0-2 into byte-col bits 4-6
__device__ __forceinline__ short8 ldsrd(const ushort* base, int row, int cb) {
  const int pcb = cb ^ ((row & 7) << 4);
  return *reinterpret_cast<const short8*>(
      reinterpret_cast<const char*>(base) + row * 128 + pcb);
}

// ---------------- 3-deep pipelined bt-GEMM (round-6 proven) ----------------
template <int MODE>
__launch_bounds__(512, 2)
__global__ void gemmP(const ushort* __restrict__ A0, const ushort* __restrict__ A1,
                      const ushort* __restrict__ A2, const ushort* __restrict__ W0,
                      const ushort* __restrict__ W1, const ushort* __restrict__ W2,
                      void* __restrict__ O0, void* __restrict__ O1,
                      void* __restrict__ O2) {
  __shared__ ushort As[3][16384];  // 256x64 each, 96 KB
  __shared__ ushort Bs[3][8192];   // 128x64 each, 48 KB
  const int tid = threadIdx.x;
  const int lane = tid & 63, w = tid >> 6;
  const int wm = w >> 1, wn = w & 1;
  const int g = lane >> 4, lr = lane & 15;
  const int m0 = blockIdx.x * 256;
  const int ysel = (MODE == 0) ? (blockIdx.y >> 3) : 0;
  const ushort* A = (MODE == 0) ? (ysel == 0 ? A0 : ysel == 1 ? A1 : A2) : A0;
  const ushort* W = (MODE == 0) ? (ysel == 0 ? W0 : ysel == 1 ? W1 : W2) : W0;
  const int n0 = ((MODE == 0) ? (blockIdx.y & 7) : blockIdx.y) * 128;

  const int row_r = tid >> 3;
  const int cb = ((tid & 7) * 16) ^ ((row_r & 7) << 4);
  const ushort* Asrc = A + (size_t)(m0 + row_r) * DM + (cb >> 1);
  const ushort* Wsrc = W + (size_t)(n0 + row_r) * DM + (cb >> 1);

#define STG_ALL(bs, kt)                                                      \
  { const int kq = (kt) * 64;                                                \
    glds16(Asrc + kq,                        &As[bs][w * 512]);              \
    glds16(Asrc + (size_t)64 * DM + kq,      &As[bs][4096 + w * 512]);       \
    glds16(Asrc + (size_t)128 * DM + kq,     &As[bs][8192 + w * 512]);       \
    glds16(Asrc + (size_t)192 * DM + kq,     &As[bs][12288 + w * 512]);      \
    glds16(Wsrc + kq,                        &Bs[bs][w * 512]);              \
    glds16(Wsrc + (size_t)64 * DM + kq,      &Bs[bs][4096 + w * 512]); }

  f32x4 acc[4][4] = {};
  short8 af[4][2], b0[2][2], b1[2][2];

  STG_ALL(0, 0);
  STG_ALL(1, 1);

  int bc = 0;
  for (int kt = 0; kt < 16; ++kt) {
    const int bs = bc >= 1 ? bc - 1 : bc + 2;  // (bc+2)%3
    const int tn = kt + 2 < 16 ? kt + 2 : 15;
    asm volatile("s_waitcnt vmcnt(6)" ::: "memory");
    __builtin_amdgcn_s_barrier();
    __builtin_amdgcn_sched_barrier(0);
    const ushort* Ab = &As[bc][0];
    const ushort* Bb = &Bs[bc][0];
#pragma unroll
    for (int m = 0; m < 4; m++)
#pragma unroll
      for (int kk = 0; kk < 2; kk++)
        af[m][kk] = ldsrd(Ab, wm * 64 + m * 16 + lr, kk * 64 + g * 16);
#pragma unroll
    for (int n = 0; n < 2; n++)
#pragma unroll
      for (int kk = 0; kk < 2; kk++) {
        b0[n][kk] = ldsrd(Bb, wn * 64 + n * 16 + lr, kk * 64 + g * 16);
        b1[n][kk] = ldsrd(Bb, wn * 64 + 32 + n * 16 + lr, kk * 64 + g * 16);
      }
    STG_ALL(bs, tn);
    __builtin_amdgcn_sched_barrier(0);
    asm volatile("s_waitcnt lgkmcnt(0)" ::: "memory");
    __builtin_amdgcn_sched_barrier(0);
    __builtin_amdgcn_s_setprio(1);
#pragma unroll
    for (int m = 0; m < 4; m++)
#pragma unroll
      for (int n = 0; n < 2; n++)
#pragma unroll
        for (int kk = 0; kk < 2; kk++)
          acc[m][n] = __builtin_amdgcn_mfma_f32_16x16x32_bf16(af[m][kk], b0[n][kk],
                                                              acc[m][n], 0, 0, 0);
#pragma unroll
    for (int m = 0; m < 4; m++)
#pragma unroll
      for (int n = 0; n < 2; n++)
#pragma unroll
        for (int kk = 0; kk < 2; kk++)
          acc[m][2 + n] = __builtin_amdgcn_mfma_f32_16x16x32_bf16(af[m][kk], b1[n][kk],
                                                                  acc[m][2 + n], 0, 0, 0);
    __builtin_amdgcn_s_setprio(0);
    __builtin_amdgcn_sched_barrier(0);
    bc = bc + 1 == 3 ? 0 : bc + 1;
  }
#undef STG_ALL

  const int colB = n0 + wn * 64;
#pragma unroll
  for (int m = 0; m < 4; ++m) {
    const int row0 = m0 + wm * 64 + m * 16 + g * 4;
#pragma unroll
    for (int n = 0; n < 4; ++n) {
      const int col = colB + n * 16 + lr;
      if (MODE == 2) {
#pragma unroll
        for (int r = 0; r < 4; r++)
          reinterpret_cast<float*>(O0)[(size_t)(row0 + r) * DM + col] = acc[m][n][r];
      } else if (ysel == 0 || ysel == 1) {
        ushort* O = reinterpret_cast<ushort*>(ysel == 0 ? O0 : O1);
#pragma unroll
        for (int r = 0; r < 4; r++)
          O[(size_t)(row0 + r) * DM + col] = f2b(acc[m][n][r]);
      } else {
        const int b = row0 >> 12, s0 = row0 & 4095;
        const int h = col >> 6, dk = col & 63;
        ushort4 o;
        o.x = f2b(acc[m][n][0]); o.y = f2b(acc[m][n][1]);
        o.z = f2b(acc[m][n][2]); o.w = f2b(acc[m][n][3]);
        *reinterpret_cast<ushort4*>(
            reinterpret_cast<ushort*>(O2) +
            (((size_t)(b * NH + h) * DH + dk) << 12) + s0) = o;
      }
    }
  }
}

// ---------------- local attention (round-19 proven: fixed-max + remap + setprio) ----------------
__global__ void attn_local(const ushort* __restrict__ Qp, const ushort* __restrict__ Kp,
                           const ushort* __restrict__ Vt, ushort* __restrict__ Ao) {
  __shared__ ushort Ks[2][4096];
  __shared__ ushort Vs[2][4096];
  __shared__ ushort Ps[8][16 * 72];
  const int tid = threadIdx.x;
  const int lane = tid & 63;
  const int w = tid >> 6;
  const int g = lane >> 4, lr = lane & 15;
  const int bh = blockIdx.y, b = bh >> 4, h = bh & 15;
  const int qt = ((blockIdx.x & 7) << 2) + (blockIdx.x >> 3);
  const int q0 = qt * 128;

  const float C_SCALE = 0.125f * 1.44269504f;
  const float C_M = 8.0f * 1.44269504f;

  const int qrow = q0 + w * 16 + lr;
  const ushort* qptr = Qp + ((size_t)b * S_LEN + qrow) * DM + h * DH;
  short8 qf[2];
  qf[0] = *reinterpret_cast<const short8*>(qptr + g * 8);
  qf[1] = *reinterpret_cast<const short8*>(qptr + 32 + g * 8);

  float l_r[4] = {0.f, 0.f, 0.f, 0.f};
  f32x4 acc_o[4] = {};

  const int sr = tid >> 3;
  const int scb = (tid & 7) * 16;

  const int t_lo = q0 >= 128 ? q0 - 128 : 0;
  const int t_hi = (q0 + 256) <= S_LEN ? (q0 + 256) : S_LEN;

#define STAGE(bb, kk0)                                                        \
  {                                                                           \
    const int cbk = scb ^ ((sr & 7) << 4);                                    \
    glds16(Kp + ((size_t)b * S_LEN + (kk0) + sr) * DM + h * DH + cbk / 2,     \
           &Ks[bb][w * 512]);                                                 \
    glds16(Vt + (((size_t)bh * DH + sr) << 12) + (kk0) + cbk / 2,             \
           &Vs[bb][w * 512]);                                                 \
  }

  STAGE(0, t_lo);

  int it = 0;
  for (int k0 = t_lo; k0 < t_hi; k0 += 64, ++it) {
    const int cur = it & 1;
    asm volatile("s_waitcnt vmcnt(0)" ::: "memory");
    __builtin_amdgcn_s_barrier();
    __builtin_amdgcn_sched_barrier(0);
    if (k0 + 64 < t_hi) STAGE(cur ^ 1, k0 + 64);
    __builtin_amdgcn_sched_barrier(0);

    f32x4 sc[4] = {};
    __builtin_amdgcn_s_setprio(1);
#pragma unroll
    for (int kk = 0; kk < 2; kk++) {
#pragma unroll
      for (int nt = 0; nt < 4; nt++) {
        const int kr = nt * 16 + lr;
        const int cbk = (kk * 64 + g * 16) ^ ((kr & 7) << 4);
        short8 kf = *reinterpret_cast<const short8*>(
            reinterpret_cast<const char*>(&Ks[cur][0]) + kr * 128 + cbk);
        sc[nt] = __builtin_amdgcn_mfma_f32_16x16x32_bf16(qf[kk], kf, sc[nt], 0, 0, 0);
      }
    }
    __builtin_amdgcn_s_setprio(0);
    const bool edge = (k0 < q0) || (k0 > q0 + 64);
    if (edge) {
#pragma unroll
      for (int nt = 0; nt < 4; nt++) {
        const int key = k0 + nt * 16 + lr;
#pragma unroll
        for (int r = 0; r < 4; r++) {
          const int qr = q0 + w * 16 + g * 4 + r;
          int d = qr - key; d = d < 0 ? -d : d;
          float arg = fmaf(sc[nt][r], C_SCALE, -C_M);
          arg = (d <= 128) ? arg : -400.f;
          const float p = exp2f(arg);
          sc[nt][r] = p;
          l_r[r] += p;
        }
      }
    } else {
#pragma unroll
      for (int nt = 0; nt < 4; nt++)
#pragma unroll
        for (int r = 0; r < 4; r++) {
          const float p = exp2f(fmaf(sc[nt][r], C_SCALE, -C_M));
          sc[nt][r] = p;
          l_r[r] += p;
        }
    }

    ushort* myP = Ps[w];
#pragma unroll
    for (int nt = 0; nt < 4; nt++)
#pragma unroll
      for (int r = 0; r < 4; r++)
        myP[(g * 4 + r) * 72 + nt * 16 + lr] = f2b(sc[nt][r]);
    asm volatile("s_waitcnt lgkmcnt(0)" ::: "memory");
    __builtin_amdgcn_sched_barrier(0);

    __builtin_amdgcn_s_setprio(1);
#pragma unroll
    for (int kk = 0; kk < 2; kk++) {
      short8 pf2 = *reinterpret_cast<const short8*>(myP + lr * 72 + kk * 32 + g * 8);
#pragma unroll
      for (int nt = 0; nt < 4; nt++) {
        const int vr = nt * 16 + lr;
        const int cbk = (kk * 64 + g * 16) ^ ((vr & 7) << 4);
        short8 vf = *reinterpret_cast<const short8*>(
            reinterpret_cast<const char*>(&Vs[cur][0]) + vr * 128 + cbk);
        acc_o[nt] = __builtin_amdgcn_mfma_f32_16x16x32_bf16(pf2, vf, acc_o[nt], 0, 0, 0);
      }
    }
    __builtin_amdgcn_s_setprio(0);
  }
#undef STAGE

  float inv[4];
#pragma unroll
  for (int r = 0; r < 4; r++) {
    float l = l_r[r];
    l += __shfl_xor(l, 1);
    l += __shfl_xor(l, 2);
    l += __shfl_xor(l, 4);
    l += __shfl_xor(l, 8);
    inv[r] = 1.0f / l;
  }
  const int qr0 = q0 + w * 16 + g * 4;
  ushort* orow = Ao + (size_t)b * S_LEN * DM + h * DH;
#pragma unroll
  for (int nt = 0; nt < 4; nt++)
#pragma unroll
    for (int r = 0; r < 4; r++)
      orow[(size_t)(qr0 + r) * DM + nt * 16 + lr] = f2b(acc_o[nt][r] * inv[r]);
}

extern "C" void kernel_launch(void* const* d_in, const int* in_sizes, int n_in,
                              void* d_out, int out_size, void* d_ws, size_t ws_size,
                              hipStream_t stream) {
  const float* q  = (const float*)d_in[0];
  const float* k  = (const float*)d_in[1];
  const float* v  = (const float*)d_in[2];
  const float* wq = (const float*)d_in[3];
  const float* wk = (const float*)d_in[4];
  const float* wv = (const float*)d_in[5];
  const float* wo = (const float*)d_in[6];

  const size_t NX = (size_t)B_SZ * S_LEN * DM;  // 8388608
  const size_t NW = (size_t)DM * DM;            // 1048576
  if (ws_size < (7 * NX + 4 * NW) * sizeof(ushort)) return;

  ushort* ws  = (ushort*)d_ws;
  ushort* qb  = ws;
  ushort* kb  = qb + NX;
  ushort* vb  = kb + NX;
  ushort* wqb = vb + NX;
  ushort* wkb = wqb + NW;
  ushort* wvb = wkb + NW;
  ushort* wob = wvb + NW;
  ushort* Qp  = wob + NW;
  ushort* Kp  = Qp + NX;
  ushort* Vt  = Kp + NX;
  ushort* Ao  = Vt + NX;

  cvt_all<<<dim3(2048), dim3(256), 0, stream>>>(q, k, v, wq, wk, wv, wo, ws);

  gemmP<0><<<dim3(32, 24), dim3(512), 0, stream>>>(qb, kb, vb, wqb, wkb, wvb,
                                                   Qp, Kp, Vt);

  attn_local<<<dim3(32, 32), dim3(512), 0, stream>>>(Qp, Kp, Vt, Ao);

  gemmP<2><<<dim3(32, 8), dim3(512), 0, stream>>>(Ao, Ao, Ao, wob, wob, wob,
                                                  d_out, d_out, d_out);
}